// Round 6
// baseline (195.315 us; speedup 1.0000x reference)
//
#include <hip/hip_runtime.h>

namespace {
constexpr int NB = 128;
constexpr int NR = 512;
constexpr int ND = 256;
constexpr int NA = 14;

using short8 = __attribute__((ext_vector_type(8))) short;
using f32x4  = __attribute__((ext_vector_type(4))) float;

// workspace layout (ushort elements for weights, then rmap ints)
constexpr size_t WH_US  = (size_t)40 * 16 * 8 * 64 * 8;   // 2,621,440
constexpr size_t W0_OFF = WH_US;
constexpr size_t W0_US  = (size_t)20 * 16 * 64 * 8;       // 163,840
constexpr size_t RMAP_BYTE_OFF = (WH_US + W0_US) * 2;     // 5,570,560
constexpr size_t WS_NEEDED = RMAP_BYTE_OFF + NR * sizeof(int);

__device__ __forceinline__ unsigned short f2bf(float f) {
    unsigned int u = __float_as_uint(f);
    u = (u + 0x7FFFu + ((u >> 16) & 1u)) >> 16;           // RNE
    return (unsigned short)u;
}
}

// ---- converter: Wh fp32 -> bf16, A-fragment order ---------------------------
__global__ void conv_wh(const float* __restrict__ Wh, unsigned short* __restrict__ ws) {
    int g = blockIdx.x * 256 + threadIdx.x;
    if (g >= 40 * 16 * 8 * 64) return;
    const int lane = g & 63, kt = (g >> 6) & 7, mt = (g >> 9) & 15, tl = g >> 13;
    const int v = mt * 16 + (lane & 15);
    const int u0 = kt * 32 + (lane >> 4) * 8;
    const float* src = Wh + ((size_t)tl * ND + v) * ND + u0;
    unsigned short o[8];
#pragma unroll
    for (int j = 0; j < 8; ++j) o[j] = f2bf(src[j]);
    uint4 pk;
    pk.x = o[0] | ((unsigned)o[1] << 16); pk.y = o[2] | ((unsigned)o[3] << 16);
    pk.z = o[4] | ((unsigned)o[5] << 16); pk.w = o[6] | ((unsigned)o[7] << 16);
    *reinterpret_cast<uint4*>(ws + (size_t)g * 8) = pk;
}

__global__ void conv_w0(const float* __restrict__ W0, unsigned short* __restrict__ ws) {
    int g = blockIdx.x * 256 + threadIdx.x;
    if (g >= 20 * 16 * 64) return;
    const int lane = g & 63, mt = (g >> 6) & 15, t = g >> 10;
    const int v = mt * 16 + (lane & 15);
    const int a0 = (lane >> 4) * 8;
    unsigned short o[8];
#pragma unroll
    for (int j = 0; j < 8; ++j) {
        const int a = a0 + j;
        o[j] = (a < NA) ? f2bf(W0[((size_t)t * ND + v) * NA + a]) : (unsigned short)0;
    }
    uint4 pk;
    pk.x = o[0] | ((unsigned)o[1] << 16); pk.y = o[2] | ((unsigned)o[3] << 16);
    pk.z = o[4] | ((unsigned)o[5] << 16); pk.w = o[6] | ((unsigned)o[7] << 16);
    *reinterpret_cast<uint4*>(ws + W0_OFF + (size_t)g * 8) = pk;
}

// ---- type-sorted residue map (stable counting order, deterministic) --------
__global__ void build_rmap(const int* __restrict__ type_ids, int* __restrict__ rmap) {
    __shared__ int tl[NR];
    const int tid = threadIdx.x;          // 512 threads
    tl[tid] = type_ids[tid];
    __syncthreads();
    const int myt = tl[tid];
    int pos = 0;
    for (int j = 0; j < NR; ++j) {
        const int tj = tl[j];
        pos += (tj < myt) || (tj == myt && j < tid);
    }
    rmap[pos] = tid;
}

// ---- main fused kernel ------------------------------------------------------
// block = (residue rmap[bid>>3], 16-batch chunk bid&7); 48 GEMM cols n=(b-b0)*3+c
// 4 waves split M: wave w owns v in [64w, 64w+64). acc[4 m-tiles][3 n-tiles].
__global__ __launch_bounds__(256, 6) void residues_mfma(
    const float* __restrict__ x, const unsigned short* __restrict__ wsw,
    const int* __restrict__ rmap, const int* __restrict__ type_ids,
    const int* __restrict__ res_idx, float* __restrict__ out, int n_atoms)
{
    const int tid = threadIdx.x, lane = tid & 63, w = tid >> 6;
    const int r = rmap[blockIdx.x >> 3];
    const int b0 = (blockIdx.x & 7) * 16;
    const int ri = res_idx[r], t = type_ids[r];

    // HT[48][264] bf16 (25344B). Aliased (disjoint lifetimes):
    //   dltT[48][40] bf16 @ base      (layer-0 B operand)
    //   fst[48][132] f32  @ base      (epilogue restage; exactly 25344B)
    __shared__ __align__(16) unsigned short HT[48 * 264];
    unsigned short* dltT = HT;

    // hoist layer-0 A fragments (depend only on t)
    const unsigned short* w0b = wsw + W0_OFF + (size_t)t * (16 * 64 * 8);
    short8 a0[4];
#pragma unroll
    for (int mi = 0; mi < 4; ++mi)
        a0[mi] = *reinterpret_cast<const short8*>(w0b + (((w * 4 + mi) * 64) + lane) * 8);

    // ---- fused stage: dltT (bf16, K padded to 32) + pos_ca -----------------
    // task = bl*32 + k : k<16 real (clamped; k>=14 killed by W0 zero-pad), k>=16 zero
#pragma unroll
    for (int it = 0; it < 2; ++it) {
        const int task = tid + it * 256;
        const int bl = task >> 5, k = task & 31;
        const float* xb = x + (size_t)(b0 + bl) * n_atoms * 3;
        if (k < 16) {
            int atom = ri + k; if (atom > n_atoms - 1) atom = n_atoms - 1;
            const float* src  = xb + (size_t)atom * 3;
            const float* root = xb + (size_t)(ri + 1) * 3;
#pragma unroll
            for (int c = 0; c < 3; ++c)
                dltT[(bl * 3 + c) * 40 + k] = f2bf(src[c] - root[c]);
            if (k == 1) {
#pragma unroll
                for (int c = 0; c < 3; ++c)
                    out[((size_t)(b0 + bl) * NR + r) * 3 + c] = root[c];
            }
        } else {
#pragma unroll
            for (int c = 0; c < 3; ++c)
                dltT[(bl * 3 + c) * 40 + k] = 0;
        }
    }
    __syncthreads();

    f32x4 acc[4][3];
#pragma unroll
    for (int mi = 0; mi < 4; ++mi)
#pragma unroll
        for (int ni = 0; ni < 3; ++ni) acc[mi][ni] = f32x4{0.f, 0.f, 0.f, 0.f};

    // ---- layer 0: K=32 (padded), A hoisted, B from dltT --------------------
    {
        short8 bf[3];
#pragma unroll
        for (int ni = 0; ni < 3; ++ni)
            bf[ni] = *reinterpret_cast<const short8*>(&dltT[(ni * 16 + (lane & 15)) * 40 + (lane >> 4) * 8]);
#pragma unroll
        for (int mi = 0; mi < 4; ++mi)
#pragma unroll
            for (int ni = 0; ni < 3; ++ni)
                acc[mi][ni] = __builtin_amdgcn_mfma_f32_16x16x32_bf16(a0[mi], bf[ni], acc[mi][ni], 0, 0, 0);
    }
    __syncthreads();   // dltT reads done before HT overwrite (aliased)

    // ---- hidden layers ------------------------------------------------------
#pragma unroll 1
    for (int l = 0; l < 2; ++l) {
#pragma unroll
        for (int mi = 0; mi < 4; ++mi)
#pragma unroll
            for (int ni = 0; ni < 3; ++ni) {
                const int v0 = w * 64 + mi * 16 + (lane >> 4) * 4;
                const int n  = ni * 16 + (lane & 15);
                const unsigned lo = (unsigned)f2bf(acc[mi][ni][0]) | ((unsigned)f2bf(acc[mi][ni][1]) << 16);
                const unsigned hi = (unsigned)f2bf(acc[mi][ni][2]) | ((unsigned)f2bf(acc[mi][ni][3]) << 16);
                *reinterpret_cast<uint2*>(&HT[n * 264 + v0]) = make_uint2(lo, hi);
            }
        __syncthreads();

#pragma unroll
        for (int mi = 0; mi < 4; ++mi)
#pragma unroll
            for (int ni = 0; ni < 3; ++ni) acc[mi][ni] = f32x4{0.f, 0.f, 0.f, 0.f};

        const unsigned short* wl = wsw + (size_t)(t * 2 + l) * (16 * 8 * 64 * 8);
        for (int kt = 0; kt < 8; ++kt) {
            short8 a[4], bf[3];
#pragma unroll
            for (int mi = 0; mi < 4; ++mi)
                a[mi] = *reinterpret_cast<const short8*>(wl + ((((w * 4 + mi) * 8 + kt) * 64) + lane) * 8);
#pragma unroll
            for (int ni = 0; ni < 3; ++ni)
                bf[ni] = *reinterpret_cast<const short8*>(&HT[(ni * 16 + (lane & 15)) * 264 + kt * 32 + (lane >> 4) * 8]);
#pragma unroll
            for (int mi = 0; mi < 4; ++mi)
#pragma unroll
                for (int ni = 0; ni < 3; ++ni)
                    acc[mi][ni] = __builtin_amdgcn_mfma_f32_16x16x32_bf16(a[mi], bf[ni], acc[mi][ni], 0, 0, 0);
        }
        if (l == 0) __syncthreads();
    }

    // ---- epilogue: fp32 restage through LDS, coalesced f32x4 stores --------
    float* fst  = reinterpret_cast<float*>(HT);         // [48][132]
    float* outh = out + (size_t)NB * NR * 3;
#pragma unroll 1
    for (int p = 0; p < 2; ++p) {
        __syncthreads();                                // p=0: HT reads done; p=1: stores done
        if ((w >> 1) == p) {
            const int wl_ = w & 1;
#pragma unroll
            for (int mi = 0; mi < 4; ++mi)
#pragma unroll
                for (int ni = 0; ni < 3; ++ni) {
                    const int n = ni * 16 + (lane & 15);
#pragma unroll
                    for (int j = 0; j < 4; ++j) {
                        const int vl = wl_ * 64 + mi * 16 + (lane >> 4) * 4 + j;
                        fst[n * 132 + vl] = acc[mi][ni][j];
                    }
                }
        }
        __syncthreads();
#pragma unroll
        for (int i = 0; i < 6; ++i) {
            const int idx = tid + i * 256;        // 0..1535
            const int bl = idx / 96, g = idx % 96;
            f32x4 v4;
#pragma unroll
            for (int e = 0; e < 4; ++e) {
                const int f = 4 * g + e, c = f % 3, vp = f / 3;   // vp in [0,128)
                v4[e] = fst[(bl * 3 + c) * 132 + vp];
            }
            __builtin_nontemporal_store(v4,
                reinterpret_cast<f32x4*>(&outh[(((size_t)(b0 + bl) * NR + r) * (ND * 3)) + p * 384 + 4 * g]));
        }
    }
}

// ---- fallback (round-2 verified VALU kernel) if ws too small ---------------
__global__ __launch_bounds__(256, 3) void residues_fused_fb(
    const float* __restrict__ x, const float* __restrict__ W0,
    const float* __restrict__ Wh, const int* __restrict__ type_ids,
    const int* __restrict__ res_idx, float* __restrict__ out, int n_atoms)
{
    const int tid = threadIdx.x;
    const int r = blockIdx.x >> 4;
    const int b0 = (blockIdx.x & 15) * 8;
    const int ri = res_idx[r], t = type_ids[r];
    __shared__ float dlt[NA][24];
    __shared__ float hA[ND][24];
    __shared__ float hB[ND][24];
    for (int idx = tid; idx < 8 * NA * 3; idx += 256) {
        const int bb = idx / (NA * 3), rem = idx % (NA * 3);
        const int a = rem / 3, c = rem % 3, b = b0 + bb;
        int ca = ri + a; if (ca > n_atoms - 1) ca = n_atoms - 1;
        const float root = x[((size_t)b * n_atoms + (ri + 1)) * 3 + c];
        dlt[a][bb * 3 + c] = x[((size_t)b * n_atoms + ca) * 3 + c] - root;
        if (a == 0) out[((size_t)b * NR + r) * 3 + c] = root;
    }
    __syncthreads();
    {
        const float* w0row = W0 + ((size_t)t * ND + tid) * NA;
        float acc[24];
#pragma unroll
        for (int n = 0; n < 24; ++n) acc[n] = 0.f;
#pragma unroll
        for (int a = 0; a < NA; ++a) {
            const float wv = w0row[a];
#pragma unroll
            for (int n = 0; n < 24; ++n) acc[n] += wv * dlt[a][n];
        }
#pragma unroll
        for (int n = 0; n < 24; ++n) hA[tid][n] = acc[n];
    }
    __syncthreads();
    const float* whbase = Wh + (size_t)t * 2 * ND * ND;
#pragma unroll
    for (int l = 0; l < 2; ++l) {
        const float* wrow = whbase + ((size_t)l * ND + tid) * ND;
        const float (*hin)[24] = (l == 0) ? hA : hB;
        float (*hout)[24]      = (l == 0) ? hB : hA;
        float acc[24];
#pragma unroll
        for (int n = 0; n < 24; ++n) acc[n] = 0.f;
        for (int u = 0; u < ND; ++u) {
            const float wv = wrow[u];
#pragma unroll
            for (int n = 0; n < 24; ++n) acc[n] += wv * hin[u][n];
        }
#pragma unroll
        for (int n = 0; n < 24; ++n) hout[tid][n] = acc[n];
        __syncthreads();
    }
    float* outh = out + (size_t)NB * NR * 3;
#pragma unroll
    for (int bb = 0; bb < 8; ++bb) {
        const size_t base = ((size_t)((b0 + bb) * NR + r)) * (ND * 3);
#pragma unroll
        for (int it = 0; it < 3; ++it) {
            const int g = it * 256 + tid;
            outh[base + g] = hA[g / 3][bb * 3 + g % 3];
        }
    }
}

extern "C" void kernel_launch(void* const* d_in, const int* in_sizes, int n_in,
                              void* d_out, int out_size, void* d_ws, size_t ws_size,
                              hipStream_t stream) {
    const float* x        = (const float*)d_in[0];
    const float* W0       = (const float*)d_in[1];
    const float* Wh       = (const float*)d_in[2];
    const int*   type_ids = (const int*)d_in[3];
    const int*   res_idx  = (const int*)d_in[4];
    float* out = (float*)d_out;
    const int n_atoms = in_sizes[0] / (NB * 3);

    if (ws_size >= WS_NEEDED) {
        unsigned short* wsw = (unsigned short*)d_ws;
        int* rmap = (int*)((char*)d_ws + RMAP_BYTE_OFF);
        conv_wh<<<(40 * 16 * 8 * 64 + 255) / 256, 256, 0, stream>>>(Wh, wsw);
        conv_w0<<<(20 * 16 * 64 + 255) / 256, 256, 0, stream>>>(W0, wsw);
        build_rmap<<<1, NR, 0, stream>>>(type_ids, rmap);
        residues_mfma<<<NR * 8, 256, 0, stream>>>(x, wsw, rmap, type_ids, res_idx, out, n_atoms);
    } else {
        residues_fused_fb<<<NR * 16, 256, 0, stream>>>(x, W0, Wh, type_ids, res_idx, out, n_atoms);
    }
}

// Round 7
// 97.822 us; speedup vs baseline: 1.9966x; 1.9966x over previous
//
#include <hip/hip_runtime.h>

namespace {
constexpr int NB = 128;
constexpr int NR = 512;
constexpr int ND = 256;
constexpr int NA = 14;

using short8 = __attribute__((ext_vector_type(8))) short;
using f32x4  = __attribute__((ext_vector_type(4))) float;

// workspace layout (ushort elements for weights, then rmap ints)
constexpr size_t WH_US  = (size_t)40 * 16 * 8 * 64 * 8;   // 2,621,440
constexpr size_t W0_OFF = WH_US;
constexpr size_t W0_US  = (size_t)20 * 16 * 64 * 8;       // 163,840
constexpr size_t RMAP_BYTE_OFF = (WH_US + W0_US) * 2;     // 5,570,560
constexpr size_t WS_NEEDED = RMAP_BYTE_OFF + NR * sizeof(int);

__device__ __forceinline__ unsigned short f2bf(float f) {
    unsigned int u = __float_as_uint(f);
    u = (u + 0x7FFFu + ((u >> 16) & 1u)) >> 16;           // RNE
    return (unsigned short)u;
}
}

// ---- converter: Wh fp32 -> bf16, A-fragment order ---------------------------
__global__ void conv_wh(const float* __restrict__ Wh, unsigned short* __restrict__ ws) {
    int g = blockIdx.x * 256 + threadIdx.x;
    if (g >= 40 * 16 * 8 * 64) return;
    const int lane = g & 63, kt = (g >> 6) & 7, mt = (g >> 9) & 15, tl = g >> 13;
    const int v = mt * 16 + (lane & 15);
    const int u0 = kt * 32 + (lane >> 4) * 8;
    const float* src = Wh + ((size_t)tl * ND + v) * ND + u0;
    unsigned short o[8];
#pragma unroll
    for (int j = 0; j < 8; ++j) o[j] = f2bf(src[j]);
    uint4 pk;
    pk.x = o[0] | ((unsigned)o[1] << 16); pk.y = o[2] | ((unsigned)o[3] << 16);
    pk.z = o[4] | ((unsigned)o[5] << 16); pk.w = o[6] | ((unsigned)o[7] << 16);
    *reinterpret_cast<uint4*>(ws + (size_t)g * 8) = pk;
}

__global__ void conv_w0(const float* __restrict__ W0, unsigned short* __restrict__ ws) {
    int g = blockIdx.x * 256 + threadIdx.x;
    if (g >= 20 * 16 * 64) return;
    const int lane = g & 63, mt = (g >> 6) & 15, t = g >> 10;
    const int v = mt * 16 + (lane & 15);
    const int a0 = (lane >> 4) * 8;
    unsigned short o[8];
#pragma unroll
    for (int j = 0; j < 8; ++j) {
        const int a = a0 + j;
        o[j] = (a < NA) ? f2bf(W0[((size_t)t * ND + v) * NA + a]) : (unsigned short)0;
    }
    uint4 pk;
    pk.x = o[0] | ((unsigned)o[1] << 16); pk.y = o[2] | ((unsigned)o[3] << 16);
    pk.z = o[4] | ((unsigned)o[5] << 16); pk.w = o[6] | ((unsigned)o[7] << 16);
    *reinterpret_cast<uint4*>(ws + W0_OFF + (size_t)g * 8) = pk;
}

// ---- type-sorted residue map (stable counting order, deterministic) --------
__global__ void build_rmap(const int* __restrict__ type_ids, int* __restrict__ rmap) {
    __shared__ int tl[NR];
    const int tid = threadIdx.x;          // 512 threads
    tl[tid] = type_ids[tid];
    __syncthreads();
    const int myt = tl[tid];
    int pos = 0;
    for (int j = 0; j < NR; ++j) {
        const int tj = tl[j];
        pos += (tj < myt) || (tj == myt && j < tid);
    }
    rmap[pos] = tid;
}

// ---- main fused kernel ------------------------------------------------------
// 2048 blocks, 512 threads (8 waves). XCD-affine: xcd = bid&7 owns sorted
// residue positions [64*xcd, 64*xcd+64) -> ~2-3 types -> Wh L2-resident.
// Wave w owns v in [32w, 32w+32): acc[2 m-frags][6 n-frags]; 96 cols = 32 batches.
__global__ __launch_bounds__(512, 4) void residues_mfma(
    const float* __restrict__ x, const unsigned short* __restrict__ wsw,
    const int* __restrict__ rmap, const int* __restrict__ type_ids,
    const int* __restrict__ res_idx, float* __restrict__ out, int n_atoms)
{
    const int tid = threadIdx.x, lane = tid & 63, w = tid >> 6;
    const int xcd = blockIdx.x & 7, j = blockIdx.x >> 3;      // j in [0,256)
    const int r = rmap[xcd * 64 + (j >> 2)];
    const int b0 = (j & 3) * 32;
    const int ri = res_idx[r], t = type_ids[r];

    // HT[96][264] bf16 (50688B). Aliased (disjoint lifetimes):
    //   dltT[96][40] bf16 @ base ; fst[96][132] f32 @ base (exactly 50688B)
    __shared__ __align__(16) unsigned short HT[96 * 264];
    unsigned short* dltT = HT;

    // hoist layer-0 A fragments (depend only on t)
    const unsigned short* w0b = wsw + W0_OFF + (size_t)t * (16 * 64 * 8);
    short8 a0[2];
#pragma unroll
    for (int mi = 0; mi < 2; ++mi)
        a0[mi] = *reinterpret_cast<const short8*>(w0b + (((w * 2 + mi) * 64) + lane) * 8);

    // ---- fused stage: dltT (bf16, K padded to 32) + pos_ca -----------------
#pragma unroll
    for (int it = 0; it < 2; ++it) {
        const int task = tid + it * 512;           // 0..1023 = 32 bl x 32 k
        const int bl = task >> 5, k = task & 31;
        const float* xb = x + (size_t)(b0 + bl) * n_atoms * 3;
        if (k < 16) {
            int atom = ri + k; if (atom > n_atoms - 1) atom = n_atoms - 1;
            const float* src  = xb + (size_t)atom * 3;
            const float* root = xb + (size_t)(ri + 1) * 3;
#pragma unroll
            for (int c = 0; c < 3; ++c)
                dltT[(bl * 3 + c) * 40 + k] = f2bf(src[c] - root[c]);
            if (k == 1) {
#pragma unroll
                for (int c = 0; c < 3; ++c)
                    out[((size_t)(b0 + bl) * NR + r) * 3 + c] = root[c];
            }
        } else {
#pragma unroll
            for (int c = 0; c < 3; ++c)
                dltT[(bl * 3 + c) * 40 + k] = 0;
        }
    }
    __syncthreads();

    f32x4 acc[2][6];
#pragma unroll
    for (int mi = 0; mi < 2; ++mi)
#pragma unroll
        for (int ni = 0; ni < 6; ++ni) acc[mi][ni] = f32x4{0.f, 0.f, 0.f, 0.f};

    // ---- layer 0: K=32 (padded), A hoisted, B from dltT --------------------
    {
        short8 bf[6];
#pragma unroll
        for (int ni = 0; ni < 6; ++ni)
            bf[ni] = *reinterpret_cast<const short8*>(&dltT[(ni * 16 + (lane & 15)) * 40 + (lane >> 4) * 8]);
#pragma unroll
        for (int mi = 0; mi < 2; ++mi)
#pragma unroll
            for (int ni = 0; ni < 6; ++ni)
                acc[mi][ni] = __builtin_amdgcn_mfma_f32_16x16x32_bf16(a0[mi], bf[ni], acc[mi][ni], 0, 0, 0);
    }
    __syncthreads();   // dltT reads done before HT overwrite (aliased)

    // ---- hidden layers ------------------------------------------------------
#pragma unroll 1
    for (int l = 0; l < 2; ++l) {
#pragma unroll
        for (int mi = 0; mi < 2; ++mi)
#pragma unroll
            for (int ni = 0; ni < 6; ++ni) {
                const int v0 = w * 32 + mi * 16 + (lane >> 4) * 4;
                const int n  = ni * 16 + (lane & 15);
                const unsigned lo = (unsigned)f2bf(acc[mi][ni][0]) | ((unsigned)f2bf(acc[mi][ni][1]) << 16);
                const unsigned hi = (unsigned)f2bf(acc[mi][ni][2]) | ((unsigned)f2bf(acc[mi][ni][3]) << 16);
                *reinterpret_cast<uint2*>(&HT[n * 264 + v0]) = make_uint2(lo, hi);
            }
        __syncthreads();

#pragma unroll
        for (int mi = 0; mi < 2; ++mi)
#pragma unroll
            for (int ni = 0; ni < 6; ++ni) acc[mi][ni] = f32x4{0.f, 0.f, 0.f, 0.f};

        const unsigned short* wl = wsw + (size_t)(t * 2 + l) * (16 * 8 * 64 * 8);
        // register prefetch pipeline over kt (weight loads hide under MFMA)
        short8 a_cur[2], a_nxt[2];
#pragma unroll
        for (int mi = 0; mi < 2; ++mi)
            a_cur[mi] = *reinterpret_cast<const short8*>(wl + ((((w * 2 + mi) * 8) * 64) + lane) * 8);
#pragma unroll 1
        for (int kt = 0; kt < 8; ++kt) {
            if (kt < 7) {
#pragma unroll
                for (int mi = 0; mi < 2; ++mi)
                    a_nxt[mi] = *reinterpret_cast<const short8*>(wl + ((((w * 2 + mi) * 8 + kt + 1) * 64) + lane) * 8);
            }
            short8 bf[6];
#pragma unroll
            for (int ni = 0; ni < 6; ++ni)
                bf[ni] = *reinterpret_cast<const short8*>(&HT[(ni * 16 + (lane & 15)) * 264 + kt * 32 + (lane >> 4) * 8]);
#pragma unroll
            for (int mi = 0; mi < 2; ++mi)
#pragma unroll
                for (int ni = 0; ni < 6; ++ni)
                    acc[mi][ni] = __builtin_amdgcn_mfma_f32_16x16x32_bf16(a_cur[mi], bf[ni], acc[mi][ni], 0, 0, 0);
#pragma unroll
            for (int mi = 0; mi < 2; ++mi) a_cur[mi] = a_nxt[mi];
        }
        if (l == 0) __syncthreads();
    }

    // ---- epilogue: fp32 restage through LDS, nontemporal f32x4 stores ------
    float* fst  = reinterpret_cast<float*>(HT);         // [96][132]
    float* outh = out + (size_t)NB * NR * 3;
#pragma unroll 1
    for (int p = 0; p < 2; ++p) {
        __syncthreads();                                // p=0: HT reads done; p=1: stores done
        if ((w >> 2) == p) {
            const int wq = w & 3;
#pragma unroll
            for (int mi = 0; mi < 2; ++mi)
#pragma unroll
                for (int ni = 0; ni < 6; ++ni) {
                    const int n = ni * 16 + (lane & 15);
#pragma unroll
                    for (int jj = 0; jj < 4; ++jj) {
                        const int vl = wq * 32 + mi * 16 + (lane >> 4) * 4 + jj;
                        fst[n * 132 + vl] = acc[mi][ni][jj];
                    }
                }
        }
        __syncthreads();
#pragma unroll
        for (int i = 0; i < 6; ++i) {
            const int idx = tid + i * 512;        // 0..3071
            const int bl = idx / 96, g = idx % 96;
            f32x4 v4;
#pragma unroll
            for (int e = 0; e < 4; ++e) {
                const int f = 4 * g + e, c = f % 3, vp = f / 3;   // vp in [0,128)
                v4[e] = fst[(bl * 3 + c) * 132 + vp];
            }
            __builtin_nontemporal_store(v4,
                reinterpret_cast<f32x4*>(&outh[(((size_t)(b0 + bl) * NR + r) * (ND * 3)) + p * 384 + 4 * g]));
        }
    }
}

// ---- fallback (round-2 verified VALU kernel) if ws too small ---------------
__global__ __launch_bounds__(256, 3) void residues_fused_fb(
    const float* __restrict__ x, const float* __restrict__ W0,
    const float* __restrict__ Wh, const int* __restrict__ type_ids,
    const int* __restrict__ res_idx, float* __restrict__ out, int n_atoms)
{
    const int tid = threadIdx.x;
    const int r = blockIdx.x >> 4;
    const int b0 = (blockIdx.x & 15) * 8;
    const int ri = res_idx[r], t = type_ids[r];
    __shared__ float dlt[NA][24];
    __shared__ float hA[ND][24];
    __shared__ float hB[ND][24];
    for (int idx = tid; idx < 8 * NA * 3; idx += 256) {
        const int bb = idx / (NA * 3), rem = idx % (NA * 3);
        const int a = rem / 3, c = rem % 3, b = b0 + bb;
        int ca = ri + a; if (ca > n_atoms - 1) ca = n_atoms - 1;
        const float root = x[((size_t)b * n_atoms + (ri + 1)) * 3 + c];
        dlt[a][bb * 3 + c] = x[((size_t)b * n_atoms + ca) * 3 + c] - root;
        if (a == 0) out[((size_t)b * NR + r) * 3 + c] = root;
    }
    __syncthreads();
    {
        const float* w0row = W0 + ((size_t)t * ND + tid) * NA;
        float acc[24];
#pragma unroll
        for (int n = 0; n < 24; ++n) acc[n] = 0.f;
#pragma unroll
        for (int a = 0; a < NA; ++a) {
            const float wv = w0row[a];
#pragma unroll
            for (int n = 0; n < 24; ++n) acc[n] += wv * dlt[a][n];
        }
#pragma unroll
        for (int n = 0; n < 24; ++n) hA[tid][n] = acc[n];
    }
    __syncthreads();
    const float* whbase = Wh + (size_t)t * 2 * ND * ND;
#pragma unroll
    for (int l = 0; l < 2; ++l) {
        const float* wrow = whbase + ((size_t)l * ND + tid) * ND;
        const float (*hin)[24] = (l == 0) ? hA : hB;
        float (*hout)[24]      = (l == 0) ? hB : hA;
        float acc[24];
#pragma unroll
        for (int n = 0; n < 24; ++n) acc[n] = 0.f;
        for (int u = 0; u < ND; ++u) {
            const float wv = wrow[u];
#pragma unroll
            for (int n = 0; n < 24; ++n) acc[n] += wv * hin[u][n];
        }
#pragma unroll
        for (int n = 0; n < 24; ++n) hout[tid][n] = acc[n];
        __syncthreads();
    }
    float* outh = out + (size_t)NB * NR * 3;
#pragma unroll
    for (int bb = 0; bb < 8; ++bb) {
        const size_t base = ((size_t)((b0 + bb) * NR + r)) * (ND * 3);
#pragma unroll
        for (int it = 0; it < 3; ++it) {
            const int g = it * 256 + tid;
            outh[base + g] = hA[g / 3][bb * 3 + g % 3];
        }
    }
}

extern "C" void kernel_launch(void* const* d_in, const int* in_sizes, int n_in,
                              void* d_out, int out_size, void* d_ws, size_t ws_size,
                              hipStream_t stream) {
    const float* x        = (const float*)d_in[0];
    const float* W0       = (const float*)d_in[1];
    const float* Wh       = (const float*)d_in[2];
    const int*   type_ids = (const int*)d_in[3];
    const int*   res_idx  = (const int*)d_in[4];
    float* out = (float*)d_out;
    const int n_atoms = in_sizes[0] / (NB * 3);

    if (ws_size >= WS_NEEDED) {
        unsigned short* wsw = (unsigned short*)d_ws;
        int* rmap = (int*)((char*)d_ws + RMAP_BYTE_OFF);
        conv_wh<<<(40 * 16 * 8 * 64 + 255) / 256, 256, 0, stream>>>(Wh, wsw);
        conv_w0<<<(20 * 16 * 64 + 255) / 256, 256, 0, stream>>>(W0, wsw);
        build_rmap<<<1, NR, 0, stream>>>(type_ids, rmap);
        residues_mfma<<<NR * 4, 512, 0, stream>>>(x, wsw, rmap, type_ids, res_idx, out, n_atoms);
    } else {
        residues_fused_fb<<<NR * 16, 256, 0, stream>>>(x, W0, Wh, type_ids, res_idx, out, n_atoms);
    }
}